// Round 1
// baseline (2900.192 us; speedup 1.0000x reference)
//
#include <hip/hip_runtime.h>
#include <hip/hip_bf16.h>
#include <cstdint>
#include <cstddef>

// Qwen3 MoE layer: T=2048 tokens, H=1024 hidden, E=64 experts, I=768, top-K=8
#define T_TOK 2048
#define H_DIM 1024
#define E_NUM 64
#define I_DIM 768
#define K_TOP 8

typedef __attribute__((ext_vector_type(8))) __bf16 bf16x8;
typedef __attribute__((ext_vector_type(8))) unsigned short u16x8;
typedef __attribute__((ext_vector_type(4))) float f32x4;

// f32 -> bf16 RNE via bit trick (deterministic, no __bf16 arithmetic needed)
__device__ __forceinline__ unsigned short f2bf(float f) {
  uint32_t u = __builtin_bit_cast(uint32_t, f);
  u += 0x7fffu + ((u >> 16) & 1u);
  return (unsigned short)(u >> 16);
}

__device__ __forceinline__ u16x8 pack8(float4 f0, float4 f1) {
  u16x8 r;
  r[0] = f2bf(f0.x); r[1] = f2bf(f0.y); r[2] = f2bf(f0.z); r[3] = f2bf(f0.w);
  r[4] = f2bf(f1.x); r[5] = f2bf(f1.y); r[6] = f2bf(f1.z); r[7] = f2bf(f1.w);
  return r;
}

// ---------------- router: logits -> softmax -> top-8 -> renormalize ----------------
__global__ __launch_bounds__(64) void router_kernel(
    const float* __restrict__ x, const float* __restrict__ wr,
    int* __restrict__ topk_id, float* __restrict__ topk_w,
    int* __restrict__ counts) {
  const int t = blockIdx.x;
  const int e = threadIdx.x;  // one lane per expert
  const float4* xv = (const float4*)(x + (size_t)t * H_DIM);
  const float4* wv = (const float4*)(wr + (size_t)e * H_DIM);
  float acc = 0.f;
#pragma unroll 8
  for (int i = 0; i < H_DIM / 4; ++i) {
    float4 a = xv[i], b = wv[i];
    acc = fmaf(a.x, b.x, acc);
    acc = fmaf(a.y, b.y, acc);
    acc = fmaf(a.z, b.z, acc);
    acc = fmaf(a.w, b.w, acc);
  }
  // softmax over 64 experts (one value per lane)
  float m = acc;
  for (int o = 32; o; o >>= 1) m = fmaxf(m, __shfl_xor(m, o));
  float p = __expf(acc - m);
  float s = p;
  for (int o = 32; o; o >>= 1) s += __shfl_xor(s, o);
  p /= s;
  // iterative top-8 (max with lowest-index tie-break, matches lax.top_k)
  float v = p;
  int sid = 0;
  float sw = 0.f;
  for (int k = 0; k < K_TOP; ++k) {
    float bv = v;
    int bi = e;
    for (int o = 32; o; o >>= 1) {
      float ov = __shfl_xor(bv, o);
      int oi = __shfl_xor(bi, o);
      if (ov > bv || (ov == bv && oi < bi)) { bv = ov; bi = oi; }
    }
    if (e == k) { sid = bi; sw = bv; }
    if (e == bi) v = -1.f;  // remove winner
  }
  float ssum = (e < K_TOP) ? sw : 0.f;
  for (int o = 32; o; o >>= 1) ssum += __shfl_xor(ssum, o);
  if (e < K_TOP) {
    topk_id[t * K_TOP + e] = sid;
    topk_w[t * K_TOP + e] = sw / ssum;
    atomicAdd(&counts[sid], 1);
  }
}

// ---------------- prefix sum over 64 expert counts ----------------
__global__ void scan_kernel(const int* __restrict__ counts,
                            int* __restrict__ offsets, int* __restrict__ cursor) {
  if (threadIdx.x == 0) {
    int a = 0;
    for (int e = 0; e < E_NUM; ++e) {
      offsets[e] = a;
      cursor[e] = a;
      a += counts[e];
    }
  }
}

// ---------------- scatter (token, weight) pairs grouped by expert ----------------
__global__ __launch_bounds__(256) void build_kernel(
    const int* __restrict__ topk_id, const float* __restrict__ topk_w,
    int* __restrict__ cursor, int* __restrict__ pair_token, float* __restrict__ pair_w) {
  int i = blockIdx.x * 256 + threadIdx.x;  // 16384 pairs
  int t = i >> 3;
  int e = topk_id[i];
  int pos = atomicAdd(&cursor[e], 1);
  pair_token[pos] = t;
  pair_w[pos] = topk_w[i];
}

// LDS tile: bf16 [rows][64], 8 chunks of 8 bf16 per row, XOR-swizzled chunk index
__device__ __forceinline__ int lds_idx(int row, int chunk) {
  return row * 64 + ((chunk ^ (row & 7)) * 8);
}

// ---------------- stage 1: h = silu(X Wg^T) * (X Wu^T), per expert ----------------
// grid.x = e*32 + mtile (64-token tiles), grid.y = I/128 tiles, block = 256 (4 waves)
__global__ __launch_bounds__(256) void gemm_gu_kernel(
    const float* __restrict__ x, const float* __restrict__ wg, const float* __restrict__ wu,
    const int* __restrict__ offsets, const int* __restrict__ counts,
    const int* __restrict__ pair_token, unsigned short* __restrict__ h_buf) {
  const int e = blockIdx.x >> 5;
  const int mt = blockIdx.x & 31;
  const int ne = counts[e];
  if (mt * 64 >= ne) return;
  const int off = offsets[e];
  const int nt = blockIdx.y;

  __shared__ __align__(16) unsigned short Xs[64 * 64];
  __shared__ __align__(16) unsigned short Gs[128 * 64];
  __shared__ __align__(16) unsigned short Us[128 * 64];
  __shared__ int sTok[64];

  const int tid = threadIdx.x;
  if (tid < 64) {
    int p = mt * 64 + tid;
    sTok[tid] = pair_token[off + (p < ne ? p : 0)];
  }
  __syncthreads();

  const int lane = tid & 63;
  const int wid = tid >> 6;
  const int wr = wid >> 1, wc = wid & 1;
  const int lrow = lane & 15, lk = lane >> 4;

  f32x4 accG[2][4], accU[2][4];
#pragma unroll
  for (int i = 0; i < 2; ++i)
#pragma unroll
    for (int j = 0; j < 4; ++j) {
      accG[i][j] = f32x4{0.f, 0.f, 0.f, 0.f};
      accU[i][j] = f32x4{0.f, 0.f, 0.f, 0.f};
    }

  const int xrow = tid >> 2, xq = tid & 3;    // X stage: 4 threads/row, 16 f32 each
  const int wrow = tid >> 1, whalf = tid & 1; // W stage: 2 threads/row, 32 f32 each
  const float* xsrc = x + (size_t)sTok[xrow] * H_DIM + xq * 16;
  const float* gsrc = wg + ((size_t)e * I_DIM + (size_t)nt * 128 + wrow) * H_DIM + whalf * 32;
  const float* usrc = wu + ((size_t)e * I_DIM + (size_t)nt * 128 + wrow) * H_DIM + whalf * 32;

  for (int hk = 0; hk < H_DIM; hk += 64) {
    {  // stage X (f32 -> bf16)
      const float4* s = (const float4*)(xsrc + hk);
      float4 f0 = s[0], f1 = s[1], f2 = s[2], f3 = s[3];
      *(u16x8*)&Xs[lds_idx(xrow, 2 * xq)] = pack8(f0, f1);
      *(u16x8*)&Xs[lds_idx(xrow, 2 * xq + 1)] = pack8(f2, f3);
    }
#pragma unroll
    for (int j = 0; j < 4; ++j) {  // stage Wg
      const float4* s = (const float4*)(gsrc + hk + j * 8);
      float4 f0 = s[0], f1 = s[1];
      *(u16x8*)&Gs[lds_idx(wrow, whalf * 4 + j)] = pack8(f0, f1);
    }
#pragma unroll
    for (int j = 0; j < 4; ++j) {  // stage Wu
      const float4* s = (const float4*)(usrc + hk + j * 8);
      float4 f0 = s[0], f1 = s[1];
      *(u16x8*)&Us[lds_idx(wrow, whalf * 4 + j)] = pack8(f0, f1);
    }
    __syncthreads();
#pragma unroll
    for (int ks = 0; ks < 2; ++ks) {
      bf16x8 af[2];
#pragma unroll
      for (int mi = 0; mi < 2; ++mi) {
        int r = wr * 32 + mi * 16 + lrow;
        af[mi] = __builtin_bit_cast(bf16x8, *(const u16x8*)&Xs[lds_idx(r, ks * 4 + lk)]);
      }
#pragma unroll
      for (int ni = 0; ni < 4; ++ni) {
        int r = wc * 64 + ni * 16 + lrow;
        bf16x8 bg = __builtin_bit_cast(bf16x8, *(const u16x8*)&Gs[lds_idx(r, ks * 4 + lk)]);
        bf16x8 bu = __builtin_bit_cast(bf16x8, *(const u16x8*)&Us[lds_idx(r, ks * 4 + lk)]);
#pragma unroll
        for (int mi = 0; mi < 2; ++mi) {
          accG[mi][ni] = __builtin_amdgcn_mfma_f32_16x16x32_bf16(af[mi], bg, accG[mi][ni], 0, 0, 0);
          accU[mi][ni] = __builtin_amdgcn_mfma_f32_16x16x32_bf16(af[mi], bu, accU[mi][ni], 0, 0, 0);
        }
      }
    }
    __syncthreads();
  }
  // epilogue: SwiGLU + store bf16 h
#pragma unroll
  for (int mi = 0; mi < 2; ++mi)
#pragma unroll
    for (int ni = 0; ni < 4; ++ni)
#pragma unroll
      for (int r = 0; r < 4; ++r) {
        int grow = wr * 32 + mi * 16 + lk * 4 + r;  // C/D: row=(lane>>4)*4+reg
        int p = mt * 64 + grow;
        if (p < ne) {
          int gcol = wc * 64 + ni * 16 + lrow;      // C/D: col=lane&15
          float g = accG[mi][ni][r], u = accU[mi][ni][r];
          float hv = g / (1.f + __expf(-g)) * u;    // silu(g)*u
          h_buf[(size_t)(off + p) * I_DIM + (size_t)nt * 128 + gcol] = f2bf(hv);
        }
      }
}

// ---------------- stage 2: y += route_w * (h Wd^T), per expert ----------------
// grid.x = e*32 + mtile, grid.y = H/128 tiles, block = 256 (4 waves)
__global__ __launch_bounds__(256) void gemm_down_kernel(
    const unsigned short* __restrict__ h_buf, const float* __restrict__ wd,
    const int* __restrict__ offsets, const int* __restrict__ counts,
    const int* __restrict__ pair_token, const float* __restrict__ pair_w,
    float* __restrict__ y) {
  const int e = blockIdx.x >> 5;
  const int mt = blockIdx.x & 31;
  const int ne = counts[e];
  if (mt * 64 >= ne) return;
  const int off = offsets[e];
  const int nt = blockIdx.y;

  __shared__ __align__(16) unsigned short As[64 * 64];
  __shared__ __align__(16) unsigned short Bs[128 * 64];
  __shared__ int sTok[64];
  __shared__ float sPw[64];

  const int tid = threadIdx.x;
  if (tid < 64) {
    int p = mt * 64 + tid;
    int idx = off + (p < ne ? p : 0);
    sTok[tid] = pair_token[idx];
    sPw[tid] = pair_w[idx];
  }
  __syncthreads();

  const int lane = tid & 63;
  const int wid = tid >> 6;
  const int wr = wid >> 1, wc = wid & 1;
  const int lrow = lane & 15, lk = lane >> 4;

  f32x4 acc[2][4];
#pragma unroll
  for (int i = 0; i < 2; ++i)
#pragma unroll
    for (int j = 0; j < 4; ++j) acc[i][j] = f32x4{0.f, 0.f, 0.f, 0.f};

  const int arow = tid >> 2, aq = tid & 3;
  const int brow = tid >> 1, bhalf = tid & 1;
  int ap = mt * 64 + arow;
  const unsigned short* asrc = h_buf + (size_t)(off + (ap < ne ? ap : 0)) * I_DIM + aq * 16;
  const float* bsrc = wd + ((size_t)e * H_DIM + (size_t)nt * 128 + brow) * I_DIM + bhalf * 32;

  for (int ic = 0; ic < I_DIM; ic += 64) {
    {  // stage A (already bf16)
      u16x8 a = *(const u16x8*)(asrc + ic);
      u16x8 b = *(const u16x8*)(asrc + ic + 8);
      *(u16x8*)&As[lds_idx(arow, 2 * aq)] = a;
      *(u16x8*)&As[lds_idx(arow, 2 * aq + 1)] = b;
    }
#pragma unroll
    for (int j = 0; j < 4; ++j) {  // stage Wd (f32 -> bf16)
      const float4* s = (const float4*)(bsrc + ic + j * 8);
      float4 f0 = s[0], f1 = s[1];
      *(u16x8*)&Bs[lds_idx(brow, bhalf * 4 + j)] = pack8(f0, f1);
    }
    __syncthreads();
#pragma unroll
    for (int ks = 0; ks < 2; ++ks) {
      bf16x8 af[2];
#pragma unroll
      for (int mi = 0; mi < 2; ++mi) {
        int r = wr * 32 + mi * 16 + lrow;
        af[mi] = __builtin_bit_cast(bf16x8, *(const u16x8*)&As[lds_idx(r, ks * 4 + lk)]);
      }
#pragma unroll
      for (int ni = 0; ni < 4; ++ni) {
        int r = wc * 64 + ni * 16 + lrow;
        bf16x8 bb = __builtin_bit_cast(bf16x8, *(const u16x8*)&Bs[lds_idx(r, ks * 4 + lk)]);
#pragma unroll
        for (int mi = 0; mi < 2; ++mi)
          acc[mi][ni] = __builtin_amdgcn_mfma_f32_16x16x32_bf16(af[mi], bb, acc[mi][ni], 0, 0, 0);
      }
    }
    __syncthreads();
  }
  // epilogue: scale by route weight, atomically accumulate into y
#pragma unroll
  for (int mi = 0; mi < 2; ++mi)
#pragma unroll
    for (int ni = 0; ni < 4; ++ni)
#pragma unroll
      for (int r = 0; r < 4; ++r) {
        int grow = wr * 32 + mi * 16 + lk * 4 + r;
        int p = mt * 64 + grow;
        if (p < ne) {
          int gcol = wc * 64 + ni * 16 + lrow;
          float val = acc[mi][ni][r] * sPw[grow];
          unsafeAtomicAdd(&y[(size_t)sTok[grow] * H_DIM + (size_t)nt * 128 + gcol], val);
        }
      }
}

extern "C" void kernel_launch(void* const* d_in, const int* in_sizes, int n_in,
                              void* d_out, int out_size, void* d_ws, size_t ws_size,
                              hipStream_t stream) {
  const float* x  = (const float*)d_in[0];
  const float* wr = (const float*)d_in[1];
  const float* wg = (const float*)d_in[2];
  const float* wu = (const float*)d_in[3];
  const float* wd = (const float*)d_in[4];
  float* y = (float*)d_out;

  char* ws = (char*)d_ws;
  int* counts  = (int*)ws;        // 64 ints
  int* offsets = counts + 64;     // 64 ints
  int* cursor  = counts + 128;    // 64 ints
  int*   topk_id    = (int*)(ws + 1024);                 // T*K ints   (64 KB)
  float* topk_w     = (float*)(ws + 1024 + 1 * 65536);   // T*K floats (64 KB)
  int*   pair_token = (int*)(ws + 1024 + 2 * 65536);     // T*K ints
  float* pair_w     = (float*)(ws + 1024 + 3 * 65536);   // T*K floats
  unsigned short* h_buf = (unsigned short*)(ws + 1024 + 4 * 65536);  // T*K*I bf16 (~25 MB)

  hipMemsetAsync(counts, 0, 256, stream);
  hipMemsetAsync(y, 0, (size_t)T_TOK * H_DIM * sizeof(float), stream);

  router_kernel<<<T_TOK, 64, 0, stream>>>(x, wr, topk_id, topk_w, counts);
  scan_kernel<<<1, 64, 0, stream>>>(counts, offsets, cursor);
  build_kernel<<<(T_TOK * K_TOP) / 256, 256, 0, stream>>>(topk_id, topk_w, cursor, pair_token, pair_w);
  gemm_gu_kernel<<<dim3(E_NUM * 32, I_DIM / 128), 256, 0, stream>>>(
      x, wg, wu, offsets, counts, pair_token, h_buf);
  gemm_down_kernel<<<dim3(E_NUM * 32, H_DIM / 128), 256, 0, stream>>>(
      h_buf, wd, offsets, counts, pair_token, pair_w, y);
}

// Round 2
// 2009.014 us; speedup vs baseline: 1.4436x; 1.4436x over previous
//
#include <hip/hip_runtime.h>
#include <hip/hip_bf16.h>
#include <cstdint>
#include <cstddef>

// Qwen3 MoE layer: T=2048 tokens, H=1024 hidden, E=64 experts, I=768, top-K=8
#define T_TOK 2048
#define H_DIM 1024
#define E_NUM 64
#define I_DIM 768
#define K_TOP 8

typedef __attribute__((ext_vector_type(8))) __bf16 bf16x8;
typedef __attribute__((ext_vector_type(8))) unsigned short u16x8;
typedef __attribute__((ext_vector_type(4))) float f32x4;

__device__ __forceinline__ unsigned short f2bf(float f) {
  uint32_t u = __builtin_bit_cast(uint32_t, f);
  u += 0x7fffu + ((u >> 16) & 1u);
  return (unsigned short)(u >> 16);
}

// f32x4 pair -> bf16x8 (compiler emits v_cvt_pk_bf16_f32; RNE)
__device__ __forceinline__ bf16x8 cvt8(f32x4 a, f32x4 b) {
  bf16x8 r;
  r[0] = (__bf16)a[0]; r[1] = (__bf16)a[1]; r[2] = (__bf16)a[2]; r[3] = (__bf16)a[3];
  r[4] = (__bf16)b[0]; r[5] = (__bf16)b[1]; r[6] = (__bf16)b[2]; r[7] = (__bf16)b[3];
  return r;
}

// async 16B global -> LDS (wave-uniform LDS base + lane*16; per-lane global addr)
__device__ __forceinline__ void async16(void* l, const void* g) {
  __builtin_amdgcn_global_load_lds(
      (const __attribute__((address_space(1))) unsigned int*)g,
      (__attribute__((address_space(3))) unsigned int*)l, 16, 0, 0);
}

// ---------------- router: logits -> softmax -> top-8 -> renormalize ----------------
__global__ __launch_bounds__(64) void router_kernel(
    const float* __restrict__ x, const float* __restrict__ wr,
    int* __restrict__ topk_id, float* __restrict__ topk_w,
    int* __restrict__ counts) {
  const int t = blockIdx.x;
  const int e = threadIdx.x;  // one lane per expert
  const float4* xv = (const float4*)(x + (size_t)t * H_DIM);
  const float4* wv = (const float4*)(wr + (size_t)e * H_DIM);
  float acc = 0.f;
#pragma unroll 8
  for (int i = 0; i < H_DIM / 4; ++i) {
    float4 a = xv[i], b = wv[i];
    acc = fmaf(a.x, b.x, acc);
    acc = fmaf(a.y, b.y, acc);
    acc = fmaf(a.z, b.z, acc);
    acc = fmaf(a.w, b.w, acc);
  }
  float m = acc;
  for (int o = 32; o; o >>= 1) m = fmaxf(m, __shfl_xor(m, o));
  float p = __expf(acc - m);
  float s = p;
  for (int o = 32; o; o >>= 1) s += __shfl_xor(s, o);
  p /= s;
  float v = p;
  int sid = 0;
  float sw = 0.f;
  for (int k = 0; k < K_TOP; ++k) {
    float bv = v;
    int bi = e;
    for (int o = 32; o; o >>= 1) {
      float ov = __shfl_xor(bv, o);
      int oi = __shfl_xor(bi, o);
      if (ov > bv || (ov == bv && oi < bi)) { bv = ov; bi = oi; }
    }
    if (e == k) { sid = bi; sw = bv; }
    if (e == bi) v = -1.f;
  }
  float ssum = (e < K_TOP) ? sw : 0.f;
  for (int o = 32; o; o >>= 1) ssum += __shfl_xor(ssum, o);
  if (e < K_TOP) {
    topk_id[t * K_TOP + e] = sid;
    topk_w[t * K_TOP + e] = sw / ssum;
    atomicAdd(&counts[sid], 1);
  }
}

__global__ void scan_kernel(const int* __restrict__ counts,
                            int* __restrict__ offsets, int* __restrict__ cursor) {
  if (threadIdx.x == 0) {
    int a = 0;
    for (int e = 0; e < E_NUM; ++e) {
      offsets[e] = a;
      cursor[e] = a;
      a += counts[e];
    }
  }
}

__global__ __launch_bounds__(256) void build_kernel(
    const int* __restrict__ topk_id, const float* __restrict__ topk_w,
    int* __restrict__ cursor, int* __restrict__ pair_token, float* __restrict__ pair_w) {
  int i = blockIdx.x * 256 + threadIdx.x;
  int t = i >> 3;
  int e = topk_id[i];
  int pos = atomicAdd(&cursor[e], 1);
  pair_token[pos] = t;
  pair_w[pos] = topk_w[i];
}

// ================= stage 1: h = silu(X Wg^T) * (X Wu^T) =================
// Tiles: M=128 pairs, N=64 I-cols (both G and U), BK=32 (f32 in LDS, cvt at read).
// LDS rows are 128B; chunk swizzle c^=(row&7) applied via pre-swizzled global src
// (global_load_lds writes linearly) and swizzled ds_read. 2-phase double buffer.
#define GU_BM 128
#define GU_BK 32
#define GU_BN 64
#define GU_NIT (H_DIM / GU_BK)  // 32

__global__ __launch_bounds__(256) void gemm_gu_kernel(
    const float* __restrict__ x, const float* __restrict__ wg, const float* __restrict__ wu,
    const int* __restrict__ offsets, const int* __restrict__ counts,
    const int* __restrict__ pair_token, unsigned short* __restrict__ h_buf) {
  const int e = blockIdx.x >> 4;   // 16 m-tiles of 128 (covers ne<=2048)
  const int mt = blockIdx.x & 15;
  const int ne = counts[e];
  if (mt * GU_BM >= ne) return;
  const int off = offsets[e];
  const int ib = blockIdx.y * GU_BN;

  __shared__ float Xs[2][GU_BM * GU_BK];  // 16 KB x2
  __shared__ float Gs[2][GU_BN * GU_BK];  //  8 KB x2
  __shared__ float Us[2][GU_BN * GU_BK];  //  8 KB x2
  __shared__ int sTok[GU_BM];

  const int tid = threadIdx.x;
  const int lane = tid & 63;
  const int wid = tid >> 6;

  if (tid < GU_BM) {
    int p = mt * GU_BM + tid;
    sTok[tid] = pair_token[off + (p < ne ? p : ne - 1)];
  }
  __syncthreads();

  // Precompute per-thread global sources (k0 added per iter).
  // X: 1024 chunks of 16B; this thread handles chunks wid*256 + j*64 + lane.
  const float* xp[4];
#pragma unroll
  for (int j = 0; j < 4; ++j) {
    int p = wid * 256 + j * 64 + lane;
    int row = p >> 3;
    int c = (p & 7) ^ (row & 7);  // inverse swizzle on source
    xp[j] = x + (size_t)sTok[row] * H_DIM + c * 4;
  }
  // G/U: 512 chunks each; chunks wid*128 + j*64 + lane.
  size_t goff[2];
#pragma unroll
  for (int j = 0; j < 2; ++j) {
    int p = wid * 128 + j * 64 + lane;
    int row = p >> 3;
    int c = (p & 7) ^ (row & 7);
    goff[j] = (size_t)(e * I_DIM + ib + row) * H_DIM + c * 4;
  }

  const int lrow = lane & 15, lk = lane >> 4;
  const int wrM = wid >> 1, wrN = wid & 1;

  f32x4 accG[4][2], accU[4][2];
#pragma unroll
  for (int mi = 0; mi < 4; ++mi)
#pragma unroll
    for (int ni = 0; ni < 2; ++ni) {
      accG[mi][ni] = f32x4{0.f, 0.f, 0.f, 0.f};
      accU[mi][ni] = f32x4{0.f, 0.f, 0.f, 0.f};
    }

#define GU_STAGE(b, k0)                                                   \
  do {                                                                    \
    _Pragma("unroll") for (int j = 0; j < 4; ++j)                         \
        async16(&Xs[b][(wid * 256 + j * 64) * 4], xp[j] + (k0));          \
    _Pragma("unroll") for (int j = 0; j < 2; ++j) {                       \
      async16(&Gs[b][(wid * 128 + j * 64) * 4], wg + goff[j] + (k0));     \
      async16(&Us[b][(wid * 128 + j * 64) * 4], wu + goff[j] + (k0));     \
    }                                                                     \
  } while (0)

  GU_STAGE(0, 0);
  for (int it = 0; it < GU_NIT; ++it) {
    asm volatile("s_waitcnt vmcnt(0)" ::: "memory");
    __syncthreads();  // buf[it&1] ready; all waves done with buf[(it+1)&1]
    if (it + 1 < GU_NIT) GU_STAGE((it + 1) & 1, (it + 1) * GU_BK);
    const int b = it & 1;
    bf16x8 af[4];
#pragma unroll
    for (int mi = 0; mi < 4; ++mi) {
      int row = wrM * 64 + mi * 16 + lrow;
      f32x4 a0 = *(const f32x4*)&Xs[b][row * GU_BK + (((lk * 2) ^ (row & 7)) << 2)];
      f32x4 a1 = *(const f32x4*)&Xs[b][row * GU_BK + (((lk * 2 + 1) ^ (row & 7)) << 2)];
      af[mi] = cvt8(a0, a1);
    }
#pragma unroll
    for (int ni = 0; ni < 2; ++ni) {
      int row = wrN * 32 + ni * 16 + lrow;
      int q0 = row * GU_BK + (((lk * 2) ^ (row & 7)) << 2);
      int q1 = row * GU_BK + (((lk * 2 + 1) ^ (row & 7)) << 2);
      bf16x8 bg = cvt8(*(const f32x4*)&Gs[b][q0], *(const f32x4*)&Gs[b][q1]);
      bf16x8 bu = cvt8(*(const f32x4*)&Us[b][q0], *(const f32x4*)&Us[b][q1]);
#pragma unroll
      for (int mi = 0; mi < 4; ++mi) {
        accG[mi][ni] = __builtin_amdgcn_mfma_f32_16x16x32_bf16(af[mi], bg, accG[mi][ni], 0, 0, 0);
        accU[mi][ni] = __builtin_amdgcn_mfma_f32_16x16x32_bf16(af[mi], bu, accU[mi][ni], 0, 0, 0);
      }
    }
  }
#undef GU_STAGE

#pragma unroll
  for (int mi = 0; mi < 4; ++mi)
#pragma unroll
    for (int ni = 0; ni < 2; ++ni)
#pragma unroll
      for (int r = 0; r < 4; ++r) {
        int grow = wrM * 64 + mi * 16 + lk * 4 + r;  // C/D: row=(lane>>4)*4+reg
        int p = mt * GU_BM + grow;
        if (p < ne) {
          int gcol = ib + wrN * 32 + ni * 16 + lrow;  // C/D: col=lane&15
          float g = accG[mi][ni][r], u = accU[mi][ni][r];
          float hv = g / (1.f + __expf(-g)) * u;
          h_buf[(size_t)(off + p) * I_DIM + gcol] = f2bf(hv);
        }
      }
}

// ================= stage 2: y += route_w * (h Wd^T) =================
// M=128 pairs, N=64 H-cols, BK=64. A tile bf16 [128][64], B tile f32 [64][64].
#define DN_BM 128
#define DN_BK 64
#define DN_BN 64
#define DN_NIT (I_DIM / DN_BK)  // 12

__global__ __launch_bounds__(256) void gemm_down_kernel(
    const unsigned short* __restrict__ h_buf, const float* __restrict__ wd,
    const int* __restrict__ offsets, const int* __restrict__ counts,
    const int* __restrict__ pair_token, const float* __restrict__ pair_w,
    float* __restrict__ y) {
  const int e = blockIdx.x >> 4;
  const int mt = blockIdx.x & 15;
  const int ne = counts[e];
  if (mt * DN_BM >= ne) return;
  const int off = offsets[e];
  const int hb = blockIdx.y * DN_BN;

  __shared__ unsigned short Ah[2][DN_BM * DN_BK];  // 16 KB x2
  __shared__ float Bs[2][DN_BN * DN_BK];           // 16 KB x2
  __shared__ int sTok[DN_BM];
  __shared__ float sPw[DN_BM];
  __shared__ int sHrow[DN_BM];

  const int tid = threadIdx.x;
  const int lane = tid & 63;
  const int wid = tid >> 6;

  if (tid < DN_BM) {
    int p = mt * DN_BM + tid;
    int idx = off + (p < ne ? p : ne - 1);
    sTok[tid] = pair_token[idx];
    sPw[tid] = pair_w[idx];
    sHrow[tid] = idx;
  }
  __syncthreads();

  // A: 1024 chunks (row=p>>3, CPR=8); B: 1024 chunks (row=p>>4, CPR=16)
  const unsigned short* ap[4];
  size_t boff[4];
#pragma unroll
  for (int j = 0; j < 4; ++j) {
    int p = wid * 256 + j * 64 + lane;
    int arow = p >> 3;
    int ac = (p & 7) ^ (arow & 7);
    ap[j] = h_buf + (size_t)sHrow[arow] * I_DIM + ac * 8;
    int brow = p >> 4;
    int bc = (p & 15) ^ (brow & 7);
    boff[j] = (size_t)(e * H_DIM + hb + brow) * I_DIM + bc * 4;
  }

  const int lrow = lane & 15, lk = lane >> 4;
  const int wrM = wid >> 1, wrN = wid & 1;

  f32x4 acc[4][2];
#pragma unroll
  for (int mi = 0; mi < 4; ++mi)
#pragma unroll
    for (int ni = 0; ni < 2; ++ni) acc[mi][ni] = f32x4{0.f, 0.f, 0.f, 0.f};

#define DN_STAGE(b, k0)                                                  \
  do {                                                                   \
    _Pragma("unroll") for (int j = 0; j < 4; ++j) {                      \
      async16(&Ah[b][(wid * 256 + j * 64) * 8], ap[j] + (k0));           \
      async16(&Bs[b][(wid * 256 + j * 64) * 4], wd + boff[j] + (k0));    \
    }                                                                    \
  } while (0)

  DN_STAGE(0, 0);
  for (int it = 0; it < DN_NIT; ++it) {
    asm volatile("s_waitcnt vmcnt(0)" ::: "memory");
    __syncthreads();
    if (it + 1 < DN_NIT) DN_STAGE((it + 1) & 1, (it + 1) * DN_BK);
    const int b = it & 1;
#pragma unroll
    for (int kk = 0; kk < 2; ++kk) {
      bf16x8 af[4];
#pragma unroll
      for (int mi = 0; mi < 4; ++mi) {
        int row = wrM * 64 + mi * 16 + lrow;
        af[mi] = __builtin_bit_cast(
            bf16x8, *(const u16x8*)&Ah[b][row * DN_BK + (((kk * 4 + lk) ^ (row & 7)) * 8)]);
      }
#pragma unroll
      for (int ni = 0; ni < 2; ++ni) {
        int row = wrN * 32 + ni * 16 + lrow;
        int q0 = row * DN_BK + (((kk * 8 + lk * 2) ^ (row & 7)) * 4);
        int q1 = row * DN_BK + (((kk * 8 + lk * 2 + 1) ^ (row & 7)) * 4);
        bf16x8 bb = cvt8(*(const f32x4*)&Bs[b][q0], *(const f32x4*)&Bs[b][q1]);
#pragma unroll
        for (int mi = 0; mi < 4; ++mi)
          acc[mi][ni] = __builtin_amdgcn_mfma_f32_16x16x32_bf16(af[mi], bb, acc[mi][ni], 0, 0, 0);
      }
    }
  }
#undef DN_STAGE

#pragma unroll
  for (int mi = 0; mi < 4; ++mi)
#pragma unroll
    for (int ni = 0; ni < 2; ++ni)
#pragma unroll
      for (int r = 0; r < 4; ++r) {
        int grow = wrM * 64 + mi * 16 + lk * 4 + r;
        int p = mt * DN_BM + grow;
        if (p < ne) {
          int col = hb + wrN * 32 + ni * 16 + lrow;
          float val = acc[mi][ni][r] * sPw[grow];
          unsafeAtomicAdd(&y[(size_t)sTok[grow] * H_DIM + col], val);
        }
      }
}

extern "C" void kernel_launch(void* const* d_in, const int* in_sizes, int n_in,
                              void* d_out, int out_size, void* d_ws, size_t ws_size,
                              hipStream_t stream) {
  const float* x  = (const float*)d_in[0];
  const float* wr = (const float*)d_in[1];
  const float* wg = (const float*)d_in[2];
  const float* wu = (const float*)d_in[3];
  const float* wd = (const float*)d_in[4];
  float* y = (float*)d_out;

  char* ws = (char*)d_ws;
  int* counts  = (int*)ws;
  int* offsets = counts + 64;
  int* cursor  = counts + 128;
  int*   topk_id    = (int*)(ws + 1024);
  float* topk_w     = (float*)(ws + 1024 + 1 * 65536);
  int*   pair_token = (int*)(ws + 1024 + 2 * 65536);
  float* pair_w     = (float*)(ws + 1024 + 3 * 65536);
  unsigned short* h_buf = (unsigned short*)(ws + 1024 + 4 * 65536);  // 16B-aligned, ~25 MB

  hipMemsetAsync(counts, 0, 256, stream);
  hipMemsetAsync(y, 0, (size_t)T_TOK * H_DIM * sizeof(float), stream);

  router_kernel<<<T_TOK, 64, 0, stream>>>(x, wr, topk_id, topk_w, counts);
  scan_kernel<<<1, 64, 0, stream>>>(counts, offsets, cursor);
  build_kernel<<<(T_TOK * K_TOP) / 256, 256, 0, stream>>>(topk_id, topk_w, cursor, pair_token, pair_w);
  gemm_gu_kernel<<<dim3(E_NUM * 16, I_DIM / GU_BN), 256, 0, stream>>>(
      x, wg, wu, offsets, counts, pair_token, h_buf);
  gemm_down_kernel<<<dim3(E_NUM * 16, H_DIM / DN_BN), 256, 0, stream>>>(
      h_buf, wd, offsets, counts, pair_token, pair_w, y);
}

// Round 3
// 526.401 us; speedup vs baseline: 5.5095x; 3.8165x over previous
//
#include <hip/hip_runtime.h>
#include <hip/hip_bf16.h>
#include <cstdint>
#include <cstddef>

// Qwen3 MoE layer: T=2048 tokens, H=1024 hidden, E=64 experts, I=768, top-K=8
#define T_TOK 2048
#define H_DIM 1024
#define E_NUM 64
#define I_DIM 768
#define K_TOP 8
#define MT_MAX 4  // covers ne up to 512 per expert (Binomial mean 256, sd 16)

typedef __attribute__((ext_vector_type(8))) __bf16 bf16x8;
typedef __attribute__((ext_vector_type(8))) unsigned short u16x8;
typedef __attribute__((ext_vector_type(4))) float f32x4;
typedef unsigned short ushort_t;

__device__ __forceinline__ unsigned short f2bf(float f) {
  uint32_t u = __builtin_bit_cast(uint32_t, f);
  u += 0x7fffu + ((u >> 16) & 1u);
  return (unsigned short)(u >> 16);
}

// f32x4 pair -> 8 bf16 as u16x8 (compiler emits v_cvt_pk_bf16_f32; RNE)
__device__ __forceinline__ u16x8 cvt8(f32x4 a, f32x4 b) {
  bf16x8 r;
  r[0] = (__bf16)a[0]; r[1] = (__bf16)a[1]; r[2] = (__bf16)a[2]; r[3] = (__bf16)a[3];
  r[4] = (__bf16)b[0]; r[5] = (__bf16)b[1]; r[6] = (__bf16)b[2]; r[7] = (__bf16)b[3];
  return __builtin_bit_cast(u16x8, r);
}

// ---------------- x f32 -> bf16 pre-cast (8 MB -> 4 MB, one-shot) ----------------
__global__ __launch_bounds__(256) void xcast_kernel(const float* __restrict__ x,
                                                    ushort_t* __restrict__ xb) {
  int i = blockIdx.x * 256 + threadIdx.x;  // T*H/8 = 262144 threads
  const f32x4* s = (const f32x4*)(x + (size_t)i * 8);
  *(u16x8*)(xb + (size_t)i * 8) = cvt8(s[0], s[1]);
}

// ---------------- router: logits -> softmax -> top-8 -> renormalize ----------------
__global__ __launch_bounds__(64) void router_kernel(
    const float* __restrict__ x, const float* __restrict__ wr,
    int* __restrict__ topk_id, float* __restrict__ topk_w,
    int* __restrict__ counts) {
  const int t = blockIdx.x;
  const int e = threadIdx.x;  // one lane per expert
  const float4* xv = (const float4*)(x + (size_t)t * H_DIM);
  const float4* wv = (const float4*)(wr + (size_t)e * H_DIM);
  float acc = 0.f;
#pragma unroll 8
  for (int i = 0; i < H_DIM / 4; ++i) {
    float4 a = xv[i], b = wv[i];
    acc = fmaf(a.x, b.x, acc);
    acc = fmaf(a.y, b.y, acc);
    acc = fmaf(a.z, b.z, acc);
    acc = fmaf(a.w, b.w, acc);
  }
  float m = acc;
  for (int o = 32; o; o >>= 1) m = fmaxf(m, __shfl_xor(m, o));
  float p = __expf(acc - m);
  float s = p;
  for (int o = 32; o; o >>= 1) s += __shfl_xor(s, o);
  p /= s;
  float v = p;
  int sid = 0;
  float sw = 0.f;
  for (int k = 0; k < K_TOP; ++k) {
    float bv = v;
    int bi = e;
    for (int o = 32; o; o >>= 1) {
      float ov = __shfl_xor(bv, o);
      int oi = __shfl_xor(bi, o);
      if (ov > bv || (ov == bv && oi < bi)) { bv = ov; bi = oi; }
    }
    if (e == k) { sid = bi; sw = bv; }
    if (e == bi) v = -1.f;
  }
  float ssum = (e < K_TOP) ? sw : 0.f;
  for (int o = 32; o; o >>= 1) ssum += __shfl_xor(ssum, o);
  if (e < K_TOP) {
    topk_id[t * K_TOP + e] = sid;
    topk_w[t * K_TOP + e] = sw / ssum;
    atomicAdd(&counts[sid], 1);
  }
}

__global__ void scan_kernel(const int* __restrict__ counts,
                            int* __restrict__ offsets, int* __restrict__ cursor) {
  if (threadIdx.x == 0) {
    int a = 0;
    for (int e = 0; e < E_NUM; ++e) {
      offsets[e] = a;
      cursor[e] = a;
      a += counts[e];
    }
  }
}

__global__ __launch_bounds__(256) void build_kernel(
    const int* __restrict__ topk_id, const float* __restrict__ topk_w,
    int* __restrict__ cursor, int* __restrict__ pair_token, float* __restrict__ pair_w) {
  int i = blockIdx.x * 256 + threadIdx.x;
  int t = i >> 3;
  int e = topk_id[i];
  int pos = atomicAdd(&cursor[e], 1);
  pair_token[pos] = t;
  pair_w[pos] = topk_w[i];
}

// ================= stage 1: h = silu(X Wg^T) * (X Wu^T) =================
// m93/m97 regime: BM=128, BN=64 (G and U), BK=64, bf16 LDS (32.5 KB), 4 waves,
// reg-staged with f32->bf16 cvt, single buffer, 2 barriers, 1-step reg prefetch.
// LDS rows = 64 bf16 = 8 chunks of 16B; chunk swizzle c ^= (row&7).
#define GU_NIT (H_DIM / 64)  // 16

__global__ __launch_bounds__(256, 3) void gemm_gu_kernel(
    const ushort_t* __restrict__ xb, const float* __restrict__ wg,
    const float* __restrict__ wu,
    const int* __restrict__ offsets, const int* __restrict__ counts,
    const int* __restrict__ pair_token, ushort_t* __restrict__ h_buf) {
  const int e = blockIdx.x >> 2;
  const int mt = blockIdx.x & (MT_MAX - 1);
  const int ne = counts[e];
  if (mt * 128 >= ne) return;
  const int off = offsets[e];
  const int ib = blockIdx.y * 64;

  __shared__ ushort_t Xs[128 * 64];  // 16 KB
  __shared__ ushort_t Gs[64 * 64];   //  8 KB
  __shared__ ushort_t Us[64 * 64];   //  8 KB
  __shared__ int sTok[128];

  const int tid = threadIdx.x;
  if (tid < 128) {
    int p = mt * 128 + tid;
    sTok[tid] = pair_token[off + (p < ne ? p : ne - 1)];
  }
  __syncthreads();

  // staging addresses: X = 1024 chunks (4/thread), G/U = 512 chunks (2/thread)
  const ushort_t* xsrc[4];
  int xdst[4];
#pragma unroll
  for (int j = 0; j < 4; ++j) {
    int p = j * 256 + tid;
    int row = p >> 3, c0 = p & 7;
    xsrc[j] = xb + (size_t)sTok[row] * H_DIM + c0 * 8;
    xdst[j] = (row * 8 + (c0 ^ (row & 7))) * 8;
  }
  const float* gsrc[2];
  const float* usrc[2];
  int wdst[2];
#pragma unroll
  for (int j = 0; j < 2; ++j) {
    int p = j * 256 + tid;
    int row = p >> 3, q = p & 7;
    size_t roff = ((size_t)e * I_DIM + ib + row) * H_DIM + q * 8;
    gsrc[j] = wg + roff;
    usrc[j] = wu + roff;
    wdst[j] = (row * 8 + (q ^ (row & 7))) * 8;
  }

  const int lane = tid & 63;
  const int wid = tid >> 6;
  const int mq = wid >> 1, nh = wid & 1;
  const int lrow = lane & 15, lk = lane >> 4;

  f32x4 accG[4][2], accU[4][2];
#pragma unroll
  for (int mi = 0; mi < 4; ++mi)
#pragma unroll
    for (int ni = 0; ni < 2; ++ni) {
      accG[mi][ni] = f32x4{0.f, 0.f, 0.f, 0.f};
      accU[mi][ni] = f32x4{0.f, 0.f, 0.f, 0.f};
    }

  u16x8 xr[4];
  f32x4 gr[2][2], ur[2][2];
#define GU_LOADS(k0)                                         \
  do {                                                       \
    _Pragma("unroll") for (int j = 0; j < 4; ++j)            \
        xr[j] = *(const u16x8*)(xsrc[j] + (k0));             \
    _Pragma("unroll") for (int j = 0; j < 2; ++j) {          \
      gr[j][0] = *(const f32x4*)(gsrc[j] + (k0));            \
      gr[j][1] = *(const f32x4*)(gsrc[j] + (k0) + 4);        \
      ur[j][0] = *(const f32x4*)(usrc[j] + (k0));            \
      ur[j][1] = *(const f32x4*)(usrc[j] + (k0) + 4);        \
    }                                                        \
  } while (0)

  GU_LOADS(0);
  for (int it = 0; it < GU_NIT; ++it) {
    __syncthreads();  // prior compute done reading LDS
#pragma unroll
    for (int j = 0; j < 4; ++j) *(u16x8*)&Xs[xdst[j]] = xr[j];
#pragma unroll
    for (int j = 0; j < 2; ++j) {
      *(u16x8*)&Gs[wdst[j]] = cvt8(gr[j][0], gr[j][1]);
      *(u16x8*)&Us[wdst[j]] = cvt8(ur[j][0], ur[j][1]);
    }
    if (it + 1 < GU_NIT) GU_LOADS((it + 1) * 64);  // in flight during compute
    __syncthreads();  // LDS tile ready
#pragma unroll
    for (int kk = 0; kk < 2; ++kk) {
      bf16x8 af[4];
#pragma unroll
      for (int mi = 0; mi < 4; ++mi) {
        int row = mq * 64 + mi * 16 + lrow;
        af[mi] = __builtin_bit_cast(
            bf16x8, *(const u16x8*)&Xs[(row * 8 + ((kk * 4 + lk) ^ (row & 7))) * 8]);
      }
#pragma unroll
      for (int ni = 0; ni < 2; ++ni) {
        int brow = nh * 32 + ni * 16 + lrow;
        int ch = (brow * 8 + ((kk * 4 + lk) ^ (brow & 7))) * 8;
        bf16x8 bg = __builtin_bit_cast(bf16x8, *(const u16x8*)&Gs[ch]);
        bf16x8 bu = __builtin_bit_cast(bf16x8, *(const u16x8*)&Us[ch]);
#pragma unroll
        for (int mi = 0; mi < 4; ++mi) {
          accG[mi][ni] = __builtin_amdgcn_mfma_f32_16x16x32_bf16(af[mi], bg, accG[mi][ni], 0, 0, 0);
          accU[mi][ni] = __builtin_amdgcn_mfma_f32_16x16x32_bf16(af[mi], bu, accU[mi][ni], 0, 0, 0);
        }
      }
    }
  }
#undef GU_LOADS

  // epilogue: SwiGLU + bf16 store (C/D: row=(lane>>4)*4+reg, col=lane&15)
#pragma unroll
  for (int mi = 0; mi < 4; ++mi)
#pragma unroll
    for (int ni = 0; ni < 2; ++ni)
#pragma unroll
      for (int r = 0; r < 4; ++r) {
        int grow = mq * 64 + mi * 16 + lk * 4 + r;
        int p = mt * 128 + grow;
        if (p < ne) {
          int col = ib + nh * 32 + ni * 16 + lrow;
          float g = accG[mi][ni][r], u = accU[mi][ni][r];
          float hv = g / (1.f + __expf(-g)) * u;
          h_buf[(size_t)(off + p) * I_DIM + col] = f2bf(hv);
        }
      }
}

// ================= stage 2: y += route_w * (h Wd^T) =================
// BM=128, BN=64, BK=64, bf16 LDS 24.5 KB, 4 waves, same schedule.
#define DN_NIT (I_DIM / 64)  // 12

__global__ __launch_bounds__(256, 4) void gemm_down_kernel(
    const ushort_t* __restrict__ h_buf, const float* __restrict__ wd,
    const int* __restrict__ offsets, const int* __restrict__ counts,
    const int* __restrict__ pair_token, const float* __restrict__ pair_w,
    float* __restrict__ y) {
  const int e = blockIdx.x >> 2;
  const int mt = blockIdx.x & (MT_MAX - 1);
  const int ne = counts[e];
  if (mt * 128 >= ne) return;
  const int off = offsets[e];
  const int hb = blockIdx.y * 64;

  __shared__ ushort_t Ah[128 * 64];  // 16 KB
  __shared__ ushort_t Bs[64 * 64];   //  8 KB
  __shared__ int sTok[128];
  __shared__ float sPw[128];

  const int tid = threadIdx.x;
  if (tid < 128) {
    int p = mt * 128 + tid;
    int idx = off + (p < ne ? p : ne - 1);
    sTok[tid] = pair_token[idx];
    sPw[tid] = pair_w[idx];
  }
  __syncthreads();

  const ushort_t* asrc[4];
  int adst[4];
#pragma unroll
  for (int j = 0; j < 4; ++j) {
    int p = j * 256 + tid;
    int row = p >> 3, c0 = p & 7;
    int pr = mt * 128 + row;
    asrc[j] = h_buf + (size_t)(off + (pr < ne ? pr : ne - 1)) * I_DIM + c0 * 8;
    adst[j] = (row * 8 + (c0 ^ (row & 7))) * 8;
  }
  const float* bsrc[2];
  int bdst[2];
#pragma unroll
  for (int j = 0; j < 2; ++j) {
    int p = j * 256 + tid;
    int row = p >> 3, q = p & 7;
    bsrc[j] = wd + ((size_t)e * H_DIM + hb + row) * I_DIM + q * 8;
    bdst[j] = (row * 8 + (q ^ (row & 7))) * 8;
  }

  const int lane = tid & 63;
  const int wid = tid >> 6;
  const int mq = wid >> 1, nh = wid & 1;
  const int lrow = lane & 15, lk = lane >> 4;

  f32x4 acc[4][2];
#pragma unroll
  for (int mi = 0; mi < 4; ++mi)
#pragma unroll
    for (int ni = 0; ni < 2; ++ni) acc[mi][ni] = f32x4{0.f, 0.f, 0.f, 0.f};

  u16x8 ar[4];
  f32x4 br[2][2];
#define DN_LOADS(k0)                                         \
  do {                                                       \
    _Pragma("unroll") for (int j = 0; j < 4; ++j)            \
        ar[j] = *(const u16x8*)(asrc[j] + (k0));             \
    _Pragma("unroll") for (int j = 0; j < 2; ++j) {          \
      br[j][0] = *(const f32x4*)(bsrc[j] + (k0));            \
      br[j][1] = *(const f32x4*)(bsrc[j] + (k0) + 4);        \
    }                                                        \
  } while (0)

  DN_LOADS(0);
  for (int it = 0; it < DN_NIT; ++it) {
    __syncthreads();
#pragma unroll
    for (int j = 0; j < 4; ++j) *(u16x8*)&Ah[adst[j]] = ar[j];
#pragma unroll
    for (int j = 0; j < 2; ++j) *(u16x8*)&Bs[bdst[j]] = cvt8(br[j][0], br[j][1]);
    if (it + 1 < DN_NIT) DN_LOADS((it + 1) * 64);
    __syncthreads();
#pragma unroll
    for (int kk = 0; kk < 2; ++kk) {
      bf16x8 af[4];
#pragma unroll
      for (int mi = 0; mi < 4; ++mi) {
        int row = mq * 64 + mi * 16 + lrow;
        af[mi] = __builtin_bit_cast(
            bf16x8, *(const u16x8*)&Ah[(row * 8 + ((kk * 4 + lk) ^ (row & 7))) * 8]);
      }
#pragma unroll
      for (int ni = 0; ni < 2; ++ni) {
        int brow = nh * 32 + ni * 16 + lrow;
        bf16x8 bb = __builtin_bit_cast(
            bf16x8, *(const u16x8*)&Bs[(brow * 8 + ((kk * 4 + lk) ^ (brow & 7))) * 8]);
#pragma unroll
        for (int mi = 0; mi < 4; ++mi)
          acc[mi][ni] = __builtin_amdgcn_mfma_f32_16x16x32_bf16(af[mi], bb, acc[mi][ni], 0, 0, 0);
      }
    }
  }
#undef DN_LOADS

#pragma unroll
  for (int mi = 0; mi < 4; ++mi)
#pragma unroll
    for (int ni = 0; ni < 2; ++ni)
#pragma unroll
      for (int r = 0; r < 4; ++r) {
        int grow = mq * 64 + mi * 16 + lk * 4 + r;
        int p = mt * 128 + grow;
        if (p < ne) {
          int col = hb + nh * 32 + ni * 16 + lrow;
          float val = acc[mi][ni][r] * sPw[grow];
          unsafeAtomicAdd(&y[(size_t)sTok[grow] * H_DIM + col], val);
        }
      }
}

extern "C" void kernel_launch(void* const* d_in, const int* in_sizes, int n_in,
                              void* d_out, int out_size, void* d_ws, size_t ws_size,
                              hipStream_t stream) {
  const float* x  = (const float*)d_in[0];
  const float* wr = (const float*)d_in[1];
  const float* wg = (const float*)d_in[2];
  const float* wu = (const float*)d_in[3];
  const float* wd = (const float*)d_in[4];
  float* y = (float*)d_out;

  char* ws = (char*)d_ws;
  int* counts  = (int*)ws;
  int* offsets = counts + 64;
  int* cursor  = counts + 128;
  int*   topk_id    = (int*)(ws + 1024);
  float* topk_w     = (float*)(ws + 1024 + 1 * 65536);
  int*   pair_token = (int*)(ws + 1024 + 2 * 65536);
  float* pair_w     = (float*)(ws + 1024 + 3 * 65536);
  ushort_t* h_buf = (ushort_t*)(ws + 1024 + 4 * 65536);            // 25.2 MB
  ushort_t* xb    = (ushort_t*)(ws + 1024 + 4 * 65536 + (size_t)T_TOK * I_DIM * K_TOP * 2);  // 4 MB

  hipMemsetAsync(counts, 0, 256, stream);
  hipMemsetAsync(y, 0, (size_t)T_TOK * H_DIM * sizeof(float), stream);

  xcast_kernel<<<(T_TOK * H_DIM / 8) / 256, 256, 0, stream>>>(x, xb);
  router_kernel<<<T_TOK, 64, 0, stream>>>(x, wr, topk_id, topk_w, counts);
  scan_kernel<<<1, 64, 0, stream>>>(counts, offsets, cursor);
  build_kernel<<<(T_TOK * K_TOP) / 256, 256, 0, stream>>>(topk_id, topk_w, cursor, pair_token, pair_w);
  gemm_gu_kernel<<<dim3(E_NUM * MT_MAX, I_DIM / 64), 256, 0, stream>>>(
      xb, wg, wu, offsets, counts, pair_token, h_buf);
  gemm_down_kernel<<<dim3(E_NUM * MT_MAX, H_DIM / 64), 256, 0, stream>>>(
      h_buf, wd, offsets, counts, pair_token, pair_w, y);
}

// Round 4
// 489.787 us; speedup vs baseline: 5.9213x; 1.0748x over previous
//
#include <hip/hip_runtime.h>
#include <hip/hip_bf16.h>
#include <cstdint>
#include <cstddef>

// Qwen3 MoE layer: T=2048 tokens, H=1024 hidden, E=64 experts, I=768, top-K=8
#define T_TOK 2048
#define H_DIM 1024
#define E_NUM 64
#define I_DIM 768
#define K_TOP 8

typedef __attribute__((ext_vector_type(8))) __bf16 bf16x8;
typedef __attribute__((ext_vector_type(8))) unsigned short u16x8;
typedef __attribute__((ext_vector_type(4))) float f32x4;
typedef unsigned short ushort_t;

__device__ __forceinline__ unsigned short f2bf(float f) {
  uint32_t u = __builtin_bit_cast(uint32_t, f);
  u += 0x7fffu + ((u >> 16) & 1u);
  return (unsigned short)(u >> 16);
}

// f32x4 pair -> bf16x8 (v_cvt_pk_bf16_f32, RNE)
__device__ __forceinline__ bf16x8 cvt8b(f32x4 a, f32x4 b) {
  bf16x8 r;
  r[0] = (__bf16)a[0]; r[1] = (__bf16)a[1]; r[2] = (__bf16)a[2]; r[3] = (__bf16)a[3];
  r[4] = (__bf16)b[0]; r[5] = (__bf16)b[1]; r[6] = (__bf16)b[2]; r[7] = (__bf16)b[3];
  return r;
}

// async 16B global -> LDS; dest MUST be wave-uniform base (HW adds lane*16)
__device__ __forceinline__ void async16(void* l, const void* g) {
  __builtin_amdgcn_global_load_lds(
      (const __attribute__((address_space(1))) unsigned int*)g,
      (__attribute__((address_space(3))) unsigned int*)l, 16, 0, 0);
}

// ---------------- x f32 -> bf16 pre-cast ----------------
__global__ __launch_bounds__(256) void xcast_kernel(const float* __restrict__ x,
                                                    ushort_t* __restrict__ xb) {
  int i = blockIdx.x * 256 + threadIdx.x;
  const f32x4* s = (const f32x4*)(x + (size_t)i * 8);
  *(bf16x8*)(xb + (size_t)i * 8) = cvt8b(s[0], s[1]);
}

// ---------------- router ----------------
__global__ __launch_bounds__(64) void router_kernel(
    const float* __restrict__ x, const float* __restrict__ wr,
    int* __restrict__ topk_id, float* __restrict__ topk_w,
    int* __restrict__ counts) {
  const int t = blockIdx.x;
  const int e = threadIdx.x;
  const float4* xv = (const float4*)(x + (size_t)t * H_DIM);
  const float4* wv = (const float4*)(wr + (size_t)e * H_DIM);
  float acc = 0.f;
#pragma unroll 8
  for (int i = 0; i < H_DIM / 4; ++i) {
    float4 a = xv[i], b = wv[i];
    acc = fmaf(a.x, b.x, acc);
    acc = fmaf(a.y, b.y, acc);
    acc = fmaf(a.z, b.z, acc);
    acc = fmaf(a.w, b.w, acc);
  }
  float m = acc;
  for (int o = 32; o; o >>= 1) m = fmaxf(m, __shfl_xor(m, o));
  float p = __expf(acc - m);
  float s = p;
  for (int o = 32; o; o >>= 1) s += __shfl_xor(s, o);
  p /= s;
  float v = p;
  int sid = 0;
  float sw = 0.f;
  for (int k = 0; k < K_TOP; ++k) {
    float bv = v;
    int bi = e;
    for (int o = 32; o; o >>= 1) {
      float ov = __shfl_xor(bv, o);
      int oi = __shfl_xor(bi, o);
      if (ov > bv || (ov == bv && oi < bi)) { bv = ov; bi = oi; }
    }
    if (e == k) { sid = bi; sw = bv; }
    if (e == bi) v = -1.f;
  }
  float ssum = (e < K_TOP) ? sw : 0.f;
  for (int o = 32; o; o >>= 1) ssum += __shfl_xor(ssum, o);
  if (e < K_TOP) {
    topk_id[t * K_TOP + e] = sid;
    topk_w[t * K_TOP + e] = sw / ssum;
    atomicAdd(&counts[sid], 1);
  }
}

// ---------------- scan + packed tile list (BM=256, max 2 tiles/expert) ----------------
__global__ void scan_kernel(const int* __restrict__ counts,
                            int* __restrict__ offsets, int* __restrict__ cursor,
                            int* __restrict__ tile_list, int* __restrict__ n_tiles) {
  if (threadIdx.x == 0) {
    int a = 0, n = 0;
    for (int e = 0; e < E_NUM; ++e) {
      offsets[e] = a;
      cursor[e] = a;
      int ne = counts[e];
      a += ne;
      int tl = (ne + 255) >> 8;
      if (tl > 2) tl = 2;
      for (int m = 0; m < tl; ++m) tile_list[n++] = (e << 2) | m;
    }
    *n_tiles = n;
  }
}

__global__ __launch_bounds__(256) void build_kernel(
    const int* __restrict__ topk_id, const float* __restrict__ topk_w,
    int* __restrict__ cursor, int* __restrict__ pair_token, float* __restrict__ pair_w) {
  int i = blockIdx.x * 256 + threadIdx.x;
  int t = i >> 3;
  int e = topk_id[i];
  int pos = atomicAdd(&cursor[e], 1);
  pair_token[pos] = t;
  pair_w[pos] = topk_w[i];
}

// Swizzles: bf16 rows of 4 chunks -> c ^ ((row>>1)&3); f32 rows of 8 chunks -> c ^ (row&7)

// ================= stage 1: h = silu(X Wg^T) * (X Wu^T) =================
// BM=256, BN=64 (G and U), BK=32, 512 thr (8 waves, 4M x 2N).
// Depth-2 DMA pipeline: global_load_lds, dbuf LDS, counted vmcnt(4).
#define GU_NIT 32
#define GU_GRID 1536  // 128 tile slots * 12 I-tiles

__global__ __launch_bounds__(512, 4) void gemm_gu_kernel(
    const ushort_t* __restrict__ xb, const float* __restrict__ wg,
    const float* __restrict__ wu,
    const int* __restrict__ offsets, const int* __restrict__ counts,
    const int* __restrict__ pair_token, const int* __restrict__ tile_list,
    const int* __restrict__ n_tiles, ushort_t* __restrict__ h_buf) {
  // XCD-contiguous decode: each XCD owns a contiguous idx range
  int wg0 = blockIdx.x;
  int idx = (wg0 & 7) * (GU_GRID / 8) + (wg0 >> 3);
  int tl = idx / 12;
  int nt = idx - tl * 12;
  if (tl >= *n_tiles) return;
  int ent = tile_list[tl];
  int e = ent >> 2, mt = ent & 3;
  int ne = counts[e], off = offsets[e];
  int ib = nt * 64;

  __shared__ __align__(16) ushort_t Xs[2][256 * 32];  // 16 KB x2 (bf16)
  __shared__ __align__(16) float Gs[2][64 * 32];      //  8 KB x2 (f32)
  __shared__ __align__(16) float Us[2][64 * 32];      //  8 KB x2
  __shared__ int sTok[256];

  const int tid = threadIdx.x;
  const int lane = tid & 63;
  const int wid = tid >> 6;
  if (tid < 256) {
    int p = mt * 256 + tid;
    sTok[tid] = pair_token[off + (p < ne ? p : ne - 1)];
  }
  __syncthreads();

  // per-thread DMA sources (inverse-swizzled); dest is linear (rule #21)
  const ushort_t* xsrc[2];
#pragma unroll
  for (int j = 0; j < 2; ++j) {
    int p = j * 512 + tid;           // chunk id 0..1023
    int row = p >> 2, c = p & 3;
    xsrc[j] = xb + (size_t)sTok[row] * H_DIM + ((c ^ ((row >> 1) & 3)) * 8);
  }
  const float *gsrc, *usrc;
  {
    int row = tid >> 3, c = tid & 7;  // chunk id 0..511
    size_t ro = ((size_t)e * I_DIM + ib + row) * H_DIM + ((c ^ (row & 7)) * 4);
    gsrc = wg + ro;
    usrc = wu + ro;
  }

  const int wrM = wid >> 1, wrN = wid & 1;
  const int lrow = lane & 15, lk = lane >> 4;

  f32x4 accG[4][2], accU[4][2];
#pragma unroll
  for (int mi = 0; mi < 4; ++mi)
#pragma unroll
    for (int ni = 0; ni < 2; ++ni) {
      accG[mi][ni] = f32x4{0.f, 0.f, 0.f, 0.f};
      accU[mi][ni] = f32x4{0.f, 0.f, 0.f, 0.f};
    }

#define GU_STAGE(b, k0)                                                \
  do {                                                                 \
    _Pragma("unroll") for (int j = 0; j < 2; ++j)                      \
        async16(&Xs[b][(j * 512 + wid * 64) * 8], xsrc[j] + (k0));     \
    async16(&Gs[b][wid * 64 * 4], gsrc + (k0));                        \
    async16(&Us[b][wid * 64 * 4], usrc + (k0));                        \
  } while (0)

  GU_STAGE(0, 0);
  GU_STAGE(1, 32);
  for (int it = 0; it < GU_NIT; ++it) {
    if (it == GU_NIT - 1) asm volatile("s_waitcnt vmcnt(0)" ::: "memory");
    else                  asm volatile("s_waitcnt vmcnt(4)" ::: "memory");
    __syncthreads();  // tile it fully in LDS (each wave waited its own DMAs)
    const int b = it & 1;
    bf16x8 af[4];
#pragma unroll
    for (int mi = 0; mi < 4; ++mi) {
      int r = wrM * 64 + mi * 16 + lrow;
      af[mi] = __builtin_bit_cast(
          bf16x8, *(const u16x8*)&Xs[b][r * 32 + ((lk ^ ((r >> 1) & 3)) * 8)]);
    }
#pragma unroll
    for (int ni = 0; ni < 2; ++ni) {
      int br = wrN * 32 + ni * 16 + lrow;
      int c0 = ((2 * lk) ^ (br & 7)) * 4;
      int c1 = ((2 * lk + 1) ^ (br & 7)) * 4;
      bf16x8 bg = cvt8b(*(const f32x4*)&Gs[b][br * 32 + c0],
                        *(const f32x4*)&Gs[b][br * 32 + c1]);
      bf16x8 bu = cvt8b(*(const f32x4*)&Us[b][br * 32 + c0],
                        *(const f32x4*)&Us[b][br * 32 + c1]);
#pragma unroll
      for (int mi = 0; mi < 4; ++mi) {
        accG[mi][ni] = __builtin_amdgcn_mfma_f32_16x16x32_bf16(af[mi], bg, accG[mi][ni], 0, 0, 0);
        accU[mi][ni] = __builtin_amdgcn_mfma_f32_16x16x32_bf16(af[mi], bu, accU[mi][ni], 0, 0, 0);
      }
    }
    __syncthreads();  // all waves done reading buf b
    if (it + 2 < GU_NIT) GU_STAGE(b, (it + 2) * 32);
  }
#undef GU_STAGE

  // epilogue: SwiGLU + bf16 store (C/D: row=(lane>>4)*4+reg, col=lane&15)
#pragma unroll
  for (int mi = 0; mi < 4; ++mi)
#pragma unroll
    for (int ni = 0; ni < 2; ++ni)
#pragma unroll
      for (int r = 0; r < 4; ++r) {
        int grow = wrM * 64 + mi * 16 + lk * 4 + r;
        int p = mt * 256 + grow;
        if (p < ne) {
          int col = ib + wrN * 32 + ni * 16 + lrow;
          float g = accG[mi][ni][r], u = accU[mi][ni][r];
          float hv = g / (1.f + __expf(-g)) * u;
          h_buf[(size_t)(off + p) * I_DIM + col] = f2bf(hv);
        }
      }
}

// ================= stage 2: y += route_w * (h Wd^T) =================
// BM=256, BN=64, BK=32, 512 thr, depth-2 DMA pipeline, vmcnt(3).
#define DN_NIT 24
#define DN_GRID 2048  // 128 tile slots * 16 H-tiles

__global__ __launch_bounds__(512, 4) void gemm_down_kernel(
    const ushort_t* __restrict__ h_buf, const float* __restrict__ wd,
    const int* __restrict__ offsets, const int* __restrict__ counts,
    const int* __restrict__ pair_token, const float* __restrict__ pair_w,
    const int* __restrict__ tile_list, const int* __restrict__ n_tiles,
    float* __restrict__ y) {
  int wg0 = blockIdx.x;
  int idx = (wg0 & 7) * (DN_GRID / 8) + (wg0 >> 3);
  int tl = idx >> 4;
  int nt = idx & 15;
  if (tl >= *n_tiles) return;
  int ent = tile_list[tl];
  int e = ent >> 2, mt = ent & 3;
  int ne = counts[e], off = offsets[e];
  int hb = nt * 64;

  __shared__ __align__(16) ushort_t Ah[2][256 * 32];  // 16 KB x2 (bf16)
  __shared__ __align__(16) float Bs[2][64 * 32];      //  8 KB x2 (f32)
  __shared__ int sTok[256];
  __shared__ float sPw[256];

  const int tid = threadIdx.x;
  const int lane = tid & 63;
  const int wid = tid >> 6;
  if (tid < 256) {
    int p = mt * 256 + tid;
    int ix = off + (p < ne ? p : ne - 1);
    sTok[tid] = pair_token[ix];
    sPw[tid] = pair_w[ix];
  }
  __syncthreads();

  const ushort_t* asrc[2];
#pragma unroll
  for (int j = 0; j < 2; ++j) {
    int p = j * 512 + tid;
    int row = p >> 2, c = p & 3;
    int pr = mt * 256 + row;
    asrc[j] = h_buf + (size_t)(off + (pr < ne ? pr : ne - 1)) * I_DIM +
              ((c ^ ((row >> 1) & 3)) * 8);
  }
  const float* bsrc;
  {
    int row = tid >> 3, c = tid & 7;
    bsrc = wd + ((size_t)e * H_DIM + hb + row) * I_DIM + ((c ^ (row & 7)) * 4);
  }

  const int wrM = wid >> 1, wrN = wid & 1;
  const int lrow = lane & 15, lk = lane >> 4;

  f32x4 acc[4][2];
#pragma unroll
  for (int mi = 0; mi < 4; ++mi)
#pragma unroll
    for (int ni = 0; ni < 2; ++ni) acc[mi][ni] = f32x4{0.f, 0.f, 0.f, 0.f};

#define DN_STAGE(b, k0)                                                \
  do {                                                                 \
    _Pragma("unroll") for (int j = 0; j < 2; ++j)                      \
        async16(&Ah[b][(j * 512 + wid * 64) * 8], asrc[j] + (k0));     \
    async16(&Bs[b][wid * 64 * 4], bsrc + (k0));                        \
  } while (0)

  DN_STAGE(0, 0);
  DN_STAGE(1, 32);
  for (int it = 0; it < DN_NIT; ++it) {
    if (it == DN_NIT - 1) asm volatile("s_waitcnt vmcnt(0)" ::: "memory");
    else                  asm volatile("s_waitcnt vmcnt(3)" ::: "memory");
    __syncthreads();
    const int b = it & 1;
    bf16x8 af[4];
#pragma unroll
    for (int mi = 0; mi < 4; ++mi) {
      int r = wrM * 64 + mi * 16 + lrow;
      af[mi] = __builtin_bit_cast(
          bf16x8, *(const u16x8*)&Ah[b][r * 32 + ((lk ^ ((r >> 1) & 3)) * 8)]);
    }
#pragma unroll
    for (int ni = 0; ni < 2; ++ni) {
      int br = wrN * 32 + ni * 16 + lrow;
      int c0 = ((2 * lk) ^ (br & 7)) * 4;
      int c1 = ((2 * lk + 1) ^ (br & 7)) * 4;
      bf16x8 bb = cvt8b(*(const f32x4*)&Bs[b][br * 32 + c0],
                        *(const f32x4*)&Bs[b][br * 32 + c1]);
#pragma unroll
      for (int mi = 0; mi < 4; ++mi)
        acc[mi][ni] = __builtin_amdgcn_mfma_f32_16x16x32_bf16(af[mi], bb, acc[mi][ni], 0, 0, 0);
    }
    __syncthreads();
    if (it + 2 < DN_NIT) DN_STAGE(b, (it + 2) * 32);
  }
#undef DN_STAGE

#pragma unroll
  for (int mi = 0; mi < 4; ++mi)
#pragma unroll
    for (int ni = 0; ni < 2; ++ni)
#pragma unroll
      for (int r = 0; r < 4; ++r) {
        int grow = wrM * 64 + mi * 16 + lk * 4 + r;
        int p = mt * 256 + grow;
        if (p < ne) {
          int col = hb + wrN * 32 + ni * 16 + lrow;
          float val = acc[mi][ni][r] * sPw[grow];
          unsafeAtomicAdd(&y[(size_t)sTok[grow] * H_DIM + col], val);
        }
      }
}

extern "C" void kernel_launch(void* const* d_in, const int* in_sizes, int n_in,
                              void* d_out, int out_size, void* d_ws, size_t ws_size,
                              hipStream_t stream) {
  const float* x  = (const float*)d_in[0];
  const float* wr = (const float*)d_in[1];
  const float* wg = (const float*)d_in[2];
  const float* wu = (const float*)d_in[3];
  const float* wd = (const float*)d_in[4];
  float* y = (float*)d_out;

  char* ws = (char*)d_ws;
  int* counts    = (int*)(ws + 0);      // 256 B
  int* offsets   = (int*)(ws + 256);
  int* cursor    = (int*)(ws + 512);
  int* n_tiles   = (int*)(ws + 768);
  int* tile_list = (int*)(ws + 1024);   // 512 B
  int*   topk_id    = (int*)(ws + 2048);
  float* topk_w     = (float*)(ws + 2048 + 1 * 65536);
  int*   pair_token = (int*)(ws + 2048 + 2 * 65536);
  float* pair_w     = (float*)(ws + 2048 + 3 * 65536);
  ushort_t* h_buf = (ushort_t*)(ws + 2048 + 4 * 65536);  // 25.2 MB
  ushort_t* xb = (ushort_t*)(ws + 2048 + 4 * 65536 + (size_t)T_TOK * I_DIM * K_TOP * 2);  // 4 MB

  hipMemsetAsync(counts, 0, 256, stream);
  hipMemsetAsync(y, 0, (size_t)T_TOK * H_DIM * sizeof(float), stream);

  xcast_kernel<<<(T_TOK * H_DIM / 8) / 256, 256, 0, stream>>>(x, xb);
  router_kernel<<<T_TOK, 64, 0, stream>>>(x, wr, topk_id, topk_w, counts);
  scan_kernel<<<1, 64, 0, stream>>>(counts, offsets, cursor, tile_list, n_tiles);
  build_kernel<<<(T_TOK * K_TOP) / 256, 256, 0, stream>>>(topk_id, topk_w, cursor, pair_token, pair_w);
  gemm_gu_kernel<<<GU_GRID, 512, 0, stream>>>(
      xb, wg, wu, offsets, counts, pair_token, tile_list, n_tiles, h_buf);
  gemm_down_kernel<<<DN_GRID, 512, 0, stream>>>(
      h_buf, wd, offsets, counts, pair_token, pair_w, tile_list, n_tiles, y);
}

// Round 5
// 476.905 us; speedup vs baseline: 6.0813x; 1.0270x over previous
//
#include <hip/hip_runtime.h>
#include <hip/hip_bf16.h>
#include <cstdint>
#include <cstddef>

// Qwen3 MoE layer: T=2048 tokens, H=1024 hidden, E=64 experts, I=768, top-K=8
#define T_TOK 2048
#define H_DIM 1024
#define E_NUM 64
#define I_DIM 768
#define K_TOP 8

typedef __attribute__((ext_vector_type(8))) __bf16 bf16x8;
typedef __attribute__((ext_vector_type(4))) __bf16 bf16x4;
typedef __attribute__((ext_vector_type(8))) unsigned short u16x8;
typedef __attribute__((ext_vector_type(4))) float f32x4;
typedef unsigned short ushort_t;

__device__ __forceinline__ unsigned short f2bf(float f) {
  uint32_t u = __builtin_bit_cast(uint32_t, f);
  u += 0x7fffu + ((u >> 16) & 1u);
  return (unsigned short)(u >> 16);
}

__device__ __forceinline__ bf16x8 cvt8b(f32x4 a, f32x4 b) {
  bf16x8 r;
  r[0] = (__bf16)a[0]; r[1] = (__bf16)a[1]; r[2] = (__bf16)a[2]; r[3] = (__bf16)a[3];
  r[4] = (__bf16)b[0]; r[5] = (__bf16)b[1]; r[6] = (__bf16)b[2]; r[7] = (__bf16)b[3];
  return r;
}

__device__ __forceinline__ bf16x4 cvt4b(f32x4 a) {
  bf16x4 r;
  r[0] = (__bf16)a[0]; r[1] = (__bf16)a[1]; r[2] = (__bf16)a[2]; r[3] = (__bf16)a[3];
  return r;
}

// async 16B global -> LDS; dest = wave-uniform base (HW adds lane*16)
__device__ __forceinline__ void async16(void* l, const void* g) {
  __builtin_amdgcn_global_load_lds(
      (const __attribute__((address_space(1))) unsigned int*)g,
      (__attribute__((address_space(3))) unsigned int*)l, 16, 0, 0);
}

// ---------------- x f32 -> bf16 pre-cast ----------------
__global__ __launch_bounds__(256) void xcast_kernel(const float* __restrict__ x,
                                                    ushort_t* __restrict__ xb) {
  int i = blockIdx.x * 256 + threadIdx.x;
  const f32x4* s = (const f32x4*)(x + (size_t)i * 8);
  *(bf16x8*)(xb + (size_t)i * 8) = cvt8b(s[0], s[1]);
}

// ---------------- router ----------------
__global__ __launch_bounds__(64) void router_kernel(
    const float* __restrict__ x, const float* __restrict__ wr,
    int* __restrict__ topk_id, float* __restrict__ topk_w,
    int* __restrict__ counts) {
  const int t = blockIdx.x;
  const int e = threadIdx.x;
  const float4* xv = (const float4*)(x + (size_t)t * H_DIM);
  const float4* wv = (const float4*)(wr + (size_t)e * H_DIM);
  float acc = 0.f;
#pragma unroll 8
  for (int i = 0; i < H_DIM / 4; ++i) {
    float4 a = xv[i], b = wv[i];
    acc = fmaf(a.x, b.x, acc);
    acc = fmaf(a.y, b.y, acc);
    acc = fmaf(a.z, b.z, acc);
    acc = fmaf(a.w, b.w, acc);
  }
  float m = acc;
  for (int o = 32; o; o >>= 1) m = fmaxf(m, __shfl_xor(m, o));
  float p = __expf(acc - m);
  float s = p;
  for (int o = 32; o; o >>= 1) s += __shfl_xor(s, o);
  p /= s;
  float v = p;
  int sid = 0;
  float sw = 0.f;
  for (int k = 0; k < K_TOP; ++k) {
    float bv = v;
    int bi = e;
    for (int o = 32; o; o >>= 1) {
      float ov = __shfl_xor(bv, o);
      int oi = __shfl_xor(bi, o);
      if (ov > bv || (ov == bv && oi < bi)) { bv = ov; bi = oi; }
    }
    if (e == k) { sid = bi; sw = bv; }
    if (e == bi) v = -1.f;
  }
  float ssum = (e < K_TOP) ? sw : 0.f;
  for (int o = 32; o; o >>= 1) ssum += __shfl_xor(ssum, o);
  if (e < K_TOP) {
    topk_id[t * K_TOP + e] = sid;
    topk_w[t * K_TOP + e] = sw / ssum;
    atomicAdd(&counts[sid], 1);
  }
}

// ---------------- scan + packed tile list (BM=256, max 2 tiles/expert) ----------------
__global__ void scan_kernel(const int* __restrict__ counts,
                            int* __restrict__ offsets, int* __restrict__ cursor,
                            int* __restrict__ tile_list, int* __restrict__ n_tiles) {
  if (threadIdx.x == 0) {
    int a = 0, n = 0;
    for (int e = 0; e < E_NUM; ++e) {
      offsets[e] = a;
      cursor[e] = a;
      int ne = counts[e];
      a += ne;
      int tl = (ne + 255) >> 8;
      if (tl > 2) tl = 2;
      for (int m = 0; m < tl; ++m) tile_list[n++] = (e << 2) | m;
    }
    *n_tiles = n;
  }
}

__global__ __launch_bounds__(256) void build_kernel(
    const int* __restrict__ topk_id, const float* __restrict__ topk_w,
    int* __restrict__ cursor, int* __restrict__ pair_token, float* __restrict__ pair_w) {
  int i = blockIdx.x * 256 + threadIdx.x;
  int t = i >> 3;
  int e = topk_id[i];
  int pos = atomicAdd(&cursor[e], 1);
  pair_token[pos] = t;
  pair_w[pos] = topk_w[i];
}

// bf16 LDS tiles: rows of 32 bf16 (64B = 4 chunks of 16B), chunk slot = c ^ ((row>>1)&3)

// ================= stage 1: h = silu(X Wg^T) * (X Wu^T) =================
// BM=256, BN=64 (G and U), BK=32, 512 thr (8 waves 4Mx2N).
// Raw s_barrier + counted vmcnt(4); X via global_load_lds (bf16), W reg-staged f32->bf16.
#define GU_NIT 32
#define GU_GRID 1536  // 128 tile slots * 12 I-tiles

__global__ __launch_bounds__(512, 4) void gemm_gu_kernel(
    const ushort_t* __restrict__ xb, const float* __restrict__ wg,
    const float* __restrict__ wu, const int* __restrict__ offsets,
    const int* __restrict__ counts, const int* __restrict__ pair_token,
    const int* __restrict__ tile_list, const int* __restrict__ n_tiles,
    ushort_t* __restrict__ h_buf) {
  int wg0 = blockIdx.x;
  int idx = (wg0 & 7) * (GU_GRID / 8) + (wg0 >> 3);  // XCD-contiguous
  int tl = idx / 12;
  int nt = idx - tl * 12;
  if (tl >= *n_tiles) return;
  int ent = tile_list[tl];
  int e = ent >> 2, mt = ent & 3;
  int ne = counts[e], off = offsets[e];
  int ib = nt * 64;
  int vr = ne - mt * 256;
  if (vr > 256) vr = 256;

  __shared__ __align__(16) ushort_t Xs[2][256 * 32];  // 16 KB x2
  __shared__ __align__(16) ushort_t Gs[2][64 * 32];   //  4 KB x2
  __shared__ __align__(16) ushort_t Us[2][64 * 32];   //  4 KB x2
  __shared__ int sTok[256];

  const int tid = threadIdx.x;
  const int lane = tid & 63;
  const int wid = tid >> 6;
  if (tid < 256) {
    int p = mt * 256 + tid;
    sTok[tid] = pair_token[off + (p < ne ? p : ne - 1)];
  }
  __syncthreads();

  // X DMA: 1024 chunks of 16B, 2 per thread; linear LDS dest + inverse-swizzled src
  const ushort_t* xsrc[2];
#pragma unroll
  for (int j = 0; j < 2; ++j) {
    int p = j * 512 + tid;
    int row = p >> 2, c = p & 3;
    xsrc[j] = xb + (size_t)sTok[row] * H_DIM + ((c ^ ((row >> 1) & 3)) << 3);
  }
  // W reg-staging: 1 f32x4 per G and U per stage; swizzled bf16x4 ds_write dest
  const int wrow = tid >> 3, wq = tid & 7;
  const float* gsrc = wg + ((size_t)e * I_DIM + ib + wrow) * H_DIM + wq * 4;
  const float* usrc = wu + ((size_t)e * I_DIM + ib + wrow) * H_DIM + wq * 4;
  const int wdsti = wrow * 32 + (((wq >> 1) ^ ((wrow >> 1) & 3)) << 3) + ((wq & 1) << 2);

  const int wrM = wid >> 1, wrN = wid & 1;
  const int lrow = lane & 15, lk = lane >> 4;
  const bool wact = (wrM * 64) < vr;  // wave-level thin-tile skip (no barriers inside)

  f32x4 accG[4][2], accU[4][2];
#pragma unroll
  for (int mi = 0; mi < 4; ++mi)
#pragma unroll
    for (int ni = 0; ni < 2; ++ni) {
      accG[mi][ni] = f32x4{0.f, 0.f, 0.f, 0.f};
      accU[mi][ni] = f32x4{0.f, 0.f, 0.f, 0.f};
    }

  f32x4 g0, u0, g1, u1;

#define GU_XDMA(B, K0)                                              \
  do {                                                              \
    async16(&Xs[B][(wid * 64) * 8], xsrc[0] + (K0));                \
    async16(&Xs[B][(512 + wid * 64) * 8], xsrc[1] + (K0));          \
  } while (0)

#define GU_BODY(B)                                                                       \
  do {                                                                                   \
    if (wact) {                                                                          \
      bf16x8 af[4];                                                                      \
      _Pragma("unroll") for (int mi = 0; mi < 4; ++mi) {                                 \
        int r = wrM * 64 + mi * 16 + lrow;                                               \
        af[mi] = __builtin_bit_cast(                                                     \
            bf16x8, *(const u16x8*)&Xs[B][r * 32 + ((lk ^ ((r >> 1) & 3)) << 3)]);       \
      }                                                                                  \
      _Pragma("unroll") for (int ni = 0; ni < 2; ++ni) {                                 \
        int br = wrN * 32 + ni * 16 + lrow;                                              \
        int ci = br * 32 + ((lk ^ ((br >> 1) & 3)) << 3);                                \
        bf16x8 bg = __builtin_bit_cast(bf16x8, *(const u16x8*)&Gs[B][ci]);               \
        bf16x8 bu = __builtin_bit_cast(bf16x8, *(const u16x8*)&Us[B][ci]);               \
        _Pragma("unroll") for (int mi = 0; mi < 4; ++mi) {                               \
          accG[mi][ni] =                                                                 \
              __builtin_amdgcn_mfma_f32_16x16x32_bf16(af[mi], bg, accG[mi][ni], 0, 0, 0);\
          accU[mi][ni] =                                                                 \
              __builtin_amdgcn_mfma_f32_16x16x32_bf16(af[mi], bu, accU[mi][ni], 0, 0, 0);\
        }                                                                                \
      }                                                                                  \
    }                                                                                    \
  } while (0)

// Per iter K (buffer B=K&1): early-issue W(K+2); body(K); bar#2; DMA X(K+2) into
// buf B; counted vmcnt -> W(K+1),X(K+1) landed; ds_write W(K+1) -> buf B^1; bar#1.
#define GU_ITER(K, B, GW, UW, GI, UI)                                    \
  do {                                                                   \
    if ((K) + 2 < GU_NIT) {                                              \
      GI = *(const f32x4*)(gsrc + ((K) + 2) * 32);                       \
      UI = *(const f32x4*)(usrc + ((K) + 2) * 32);                       \
    }                                                                    \
    GU_BODY(B);                                                          \
    asm volatile("s_waitcnt lgkmcnt(0)" ::: "memory");                   \
    __builtin_amdgcn_s_barrier();                                        \
    __builtin_amdgcn_sched_barrier(0);                                   \
    if ((K) + 2 < GU_NIT) {                                              \
      GU_XDMA(B, ((K) + 2) * 32);                                        \
      asm volatile("s_waitcnt vmcnt(4)" ::: "memory");                   \
    } else {                                                             \
      asm volatile("s_waitcnt vmcnt(0)" ::: "memory");                   \
    }                                                                    \
    if ((K) + 1 < GU_NIT) {                                              \
      *(bf16x4*)&Gs[(B) ^ 1][wdsti] = cvt4b(GW);                         \
      *(bf16x4*)&Us[(B) ^ 1][wdsti] = cvt4b(UW);                         \
    }                                                                    \
    asm volatile("s_waitcnt lgkmcnt(0)" ::: "memory");                   \
    __builtin_amdgcn_s_barrier();                                        \
    __builtin_amdgcn_sched_barrier(0);                                   \
  } while (0)

  // prologue: FIFO = [X0(2),W0(2),X1(2),W1(2)]; vmcnt(4) -> X0,W0 done
  GU_XDMA(0, 0);
  g0 = *(const f32x4*)(gsrc);
  u0 = *(const f32x4*)(usrc);
  GU_XDMA(1, 32);
  g1 = *(const f32x4*)(gsrc + 32);
  u1 = *(const f32x4*)(usrc + 32);
  asm volatile("s_waitcnt vmcnt(4)" ::: "memory");
  *(bf16x4*)&Gs[0][wdsti] = cvt4b(g0);
  *(bf16x4*)&Us[0][wdsti] = cvt4b(u0);
  asm volatile("s_waitcnt lgkmcnt(0)" ::: "memory");
  __builtin_amdgcn_s_barrier();
  __builtin_amdgcn_sched_barrier(0);

  for (int kk = 0; kk < GU_NIT; kk += 2) {
    GU_ITER(kk, 0, g1, u1, g0, u0);
    GU_ITER(kk + 1, 1, g0, u0, g1, u1);
  }
#undef GU_ITER
#undef GU_BODY
#undef GU_XDMA

  // epilogue: SwiGLU + bf16 store (C/D: row=(lane>>4)*4+reg, col=lane&15)
#pragma unroll
  for (int mi = 0; mi < 4; ++mi)
#pragma unroll
    for (int ni = 0; ni < 2; ++ni)
#pragma unroll
      for (int r = 0; r < 4; ++r) {
        int grow = wrM * 64 + mi * 16 + lk * 4 + r;
        int p = mt * 256 + grow;
        if (p < ne) {
          int col = ib + wrN * 32 + ni * 16 + lrow;
          float g = accG[mi][ni][r], u = accU[mi][ni][r];
          float hv = g / (1.f + __expf(-g)) * u;
          h_buf[(size_t)(off + p) * I_DIM + col] = f2bf(hv);
        }
      }
}

// ================= stage 2: y += route_w * (h Wd^T) =================
// BM=256, BN=64, BK=32, 512 thr; A (bf16 h) via DMA, B (wd f32) reg-staged; vmcnt(3).
#define DN_NIT 24
#define DN_GRID 2048  // 128 tile slots * 16 H-tiles

__global__ __launch_bounds__(512, 4) void gemm_down_kernel(
    const ushort_t* __restrict__ h_buf, const float* __restrict__ wd,
    const int* __restrict__ offsets, const int* __restrict__ counts,
    const int* __restrict__ pair_token, const float* __restrict__ pair_w,
    const int* __restrict__ tile_list, const int* __restrict__ n_tiles,
    float* __restrict__ y) {
  int wg0 = blockIdx.x;
  int idx = (wg0 & 7) * (DN_GRID / 8) + (wg0 >> 3);
  int tl = idx >> 4;
  int nt = idx & 15;
  if (tl >= *n_tiles) return;
  int ent = tile_list[tl];
  int e = ent >> 2, mt = ent & 3;
  int ne = counts[e], off = offsets[e];
  int hb = nt * 64;
  int vr = ne - mt * 256;
  if (vr > 256) vr = 256;

  __shared__ __align__(16) ushort_t Ah[2][256 * 32];  // 16 KB x2
  __shared__ __align__(16) ushort_t Bs[2][64 * 32];   //  4 KB x2
  __shared__ int sTok[256];
  __shared__ float sPw[256];

  const int tid = threadIdx.x;
  const int lane = tid & 63;
  const int wid = tid >> 6;
  if (tid < 256) {
    int p = mt * 256 + tid;
    int ix = off + (p < ne ? p : ne - 1);
    sTok[tid] = pair_token[ix];
    sPw[tid] = pair_w[ix];
  }
  __syncthreads();

  const ushort_t* asrc[2];
#pragma unroll
  for (int j = 0; j < 2; ++j) {
    int p = j * 512 + tid;
    int row = p >> 2, c = p & 3;
    int pr = mt * 256 + row;
    asrc[j] = h_buf + (size_t)(off + (pr < ne ? pr : ne - 1)) * I_DIM +
              ((c ^ ((row >> 1) & 3)) << 3);
  }
  const int brow = tid >> 3, bq = tid & 7;
  const float* bsrc = wd + ((size_t)e * H_DIM + hb + brow) * I_DIM + bq * 4;
  const int bdsti = brow * 32 + (((bq >> 1) ^ ((brow >> 1) & 3)) << 3) + ((bq & 1) << 2);

  const int wrM = wid >> 1, wrN = wid & 1;
  const int lrow = lane & 15, lk = lane >> 4;
  const bool wact = (wrM * 64) < vr;

  f32x4 acc[4][2];
#pragma unroll
  for (int mi = 0; mi < 4; ++mi)
#pragma unroll
    for (int ni = 0; ni < 2; ++ni) acc[mi][ni] = f32x4{0.f, 0.f, 0.f, 0.f};

  f32x4 b0, b1;

#define DN_ADMA(B, K0)                                              \
  do {                                                              \
    async16(&Ah[B][(wid * 64) * 8], asrc[0] + (K0));                \
    async16(&Ah[B][(512 + wid * 64) * 8], asrc[1] + (K0));          \
  } while (0)

#define DN_BODY(B)                                                                       \
  do {                                                                                   \
    if (wact) {                                                                          \
      bf16x8 af[4];                                                                      \
      _Pragma("unroll") for (int mi = 0; mi < 4; ++mi) {                                 \
        int r = wrM * 64 + mi * 16 + lrow;                                               \
        af[mi] = __builtin_bit_cast(                                                     \
            bf16x8, *(const u16x8*)&Ah[B][r * 32 + ((lk ^ ((r >> 1) & 3)) << 3)]);       \
      }                                                                                  \
      _Pragma("unroll") for (int ni = 0; ni < 2; ++ni) {                                 \
        int br = wrN * 32 + ni * 16 + lrow;                                              \
        bf16x8 bb = __builtin_bit_cast(                                                  \
            bf16x8, *(const u16x8*)&Bs[B][br * 32 + ((lk ^ ((br >> 1) & 3)) << 3)]);     \
        _Pragma("unroll") for (int mi = 0; mi < 4; ++mi)                                 \
            acc[mi][ni] =                                                                \
                __builtin_amdgcn_mfma_f32_16x16x32_bf16(af[mi], bb, acc[mi][ni], 0, 0, 0);\
      }                                                                                  \
    }                                                                                    \
  } while (0)

#define DN_ITER(K, B, BW, BI)                                            \
  do {                                                                   \
    if ((K) + 2 < DN_NIT) BI = *(const f32x4*)(bsrc + ((K) + 2) * 32);   \
    DN_BODY(B);                                                          \
    asm volatile("s_waitcnt lgkmcnt(0)" ::: "memory");                   \
    __builtin_amdgcn_s_barrier();                                        \
    __builtin_amdgcn_sched_barrier(0);                                   \
    if ((K) + 2 < DN_NIT) {                                              \
      DN_ADMA(B, ((K) + 2) * 32);                                        \
      asm volatile("s_waitcnt vmcnt(3)" ::: "memory");                   \
    } else {                                                             \
      asm volatile("s_waitcnt vmcnt(0)" ::: "memory");                   \
    }                                                                    \
    if ((K) + 1 < DN_NIT) *(bf16x4*)&Bs[(B) ^ 1][bdsti] = cvt4b(BW);     \
    asm volatile("s_waitcnt lgkmcnt(0)" ::: "memory");                   \
    __builtin_amdgcn_s_barrier();                                        \
    __builtin_amdgcn_sched_barrier(0);                                   \
  } while (0)

  DN_ADMA(0, 0);
  b0 = *(const f32x4*)(bsrc);
  DN_ADMA(1, 32);
  b1 = *(const f32x4*)(bsrc + 32);
  asm volatile("s_waitcnt vmcnt(3)" ::: "memory");
  *(bf16x4*)&Bs[0][bdsti] = cvt4b(b0);
  asm volatile("s_waitcnt lgkmcnt(0)" ::: "memory");
  __builtin_amdgcn_s_barrier();
  __builtin_amdgcn_sched_barrier(0);

  for (int kk = 0; kk < DN_NIT; kk += 2) {
    DN_ITER(kk, 0, b1, b0);
    DN_ITER(kk + 1, 1, b0, b1);
  }
#undef DN_ITER
#undef DN_BODY
#undef DN_ADMA

#pragma unroll
  for (int mi = 0; mi < 4; ++mi)
#pragma unroll
    for (int ni = 0; ni < 2; ++ni)
#pragma unroll
      for (int r = 0; r < 4; ++r) {
        int grow = wrM * 64 + mi * 16 + lk * 4 + r;
        int p = mt * 256 + grow;
        if (p < ne) {
          int col = hb + wrN * 32 + ni * 16 + lrow;
          float val = acc[mi][ni][r] * sPw[grow];
          unsafeAtomicAdd(&y[(size_t)sTok[grow] * H_DIM + col], val);
        }
      }
}

extern "C" void kernel_launch(void* const* d_in, const int* in_sizes, int n_in,
                              void* d_out, int out_size, void* d_ws, size_t ws_size,
                              hipStream_t stream) {
  const float* x  = (const float*)d_in[0];
  const float* wr = (const float*)d_in[1];
  const float* wg = (const float*)d_in[2];
  const float* wu = (const float*)d_in[3];
  const float* wd = (const float*)d_in[4];
  float* y = (float*)d_out;

  char* ws = (char*)d_ws;
  int* counts    = (int*)(ws + 0);
  int* offsets   = (int*)(ws + 256);
  int* cursor    = (int*)(ws + 512);
  int* n_tiles   = (int*)(ws + 768);
  int* tile_list = (int*)(ws + 1024);
  int*   topk_id    = (int*)(ws + 2048);
  float* topk_w     = (float*)(ws + 2048 + 1 * 65536);
  int*   pair_token = (int*)(ws + 2048 + 2 * 65536);
  float* pair_w     = (float*)(ws + 2048 + 3 * 65536);
  ushort_t* h_buf = (ushort_t*)(ws + 2048 + 4 * 65536);  // 25.2 MB
  ushort_t* xb = (ushort_t*)(ws + 2048 + 4 * 65536 + (size_t)T_TOK * I_DIM * K_TOP * 2);  // 4 MB

  hipMemsetAsync(counts, 0, 256, stream);
  hipMemsetAsync(y, 0, (size_t)T_TOK * H_DIM * sizeof(float), stream);

  xcast_kernel<<<(T_TOK * H_DIM / 8) / 256, 256, 0, stream>>>(x, xb);
  router_kernel<<<T_TOK, 64, 0, stream>>>(x, wr, topk_id, topk_w, counts);
  scan_kernel<<<1, 64, 0, stream>>>(counts, offsets, cursor, tile_list, n_tiles);
  build_kernel<<<(T_TOK * K_TOP) / 256, 256, 0, stream>>>(topk_id, topk_w, cursor, pair_token, pair_w);
  gemm_gu_kernel<<<GU_GRID, 512, 0, stream>>>(
      xb, wg, wu, offsets, counts, pair_token, tile_list, n_tiles, h_buf);
  gemm_down_kernel<<<DN_GRID, 512, 0, stream>>>(
      h_buf, wd, offsets, counts, pair_token, pair_w, tile_list, n_tiles, y);
}